// Round 10
// baseline (104.613 us; speedup 1.0000x reference)
//
#include <hip/hip_runtime.h>

// MyConv2D: N=32, Cin=128, H=W=56, Cout=256, K=3, stride=1, pad=1, fp32.
// R10 == R9 resubmit (R9 bench failed on container infra, kernel never ran).
// B bypasses LDS entirely. R8 was LDS-read-bound (1.85GB ds_read total,
// ~44us on the LDS pipe vs 28us MFMA). xt's 16B granule [n][g][pix][8ic] IS
// the per-lane B fragment -> each lane global_load_dwordx4's it directly
// from L2/L3 (zero-page cndmask at borders, 36-bit validity mask/lane).
// A stays LDS-staged (4x reuse across N-waves), double-buffered 32KB,
// ONE barrier per K-tile. Tile 128(oc) x 256(pix), 8 waves, per-wave 64x64.

typedef unsigned short u16;
typedef _Float16 f16x8 __attribute__((ext_vector_type(8)));
typedef float f32x4 __attribute__((ext_vector_type(4)));

#define CIN    128
#define COUT   256
#define HW     56
#define NPIX   3136        // 56*56
#define TOTPIX 100352      // 32*3136
#define NKT    18          // K-tiles of 64 ic: 9 taps * 2 ic-halves

#define WAITVM0 asm volatile("s_waitcnt vmcnt(0)" ::: "memory")
#define BARRIER asm volatile("s_barrier" ::: "memory")

__device__ __forceinline__ void gload16(const void* g, void* l) {
  __builtin_amdgcn_global_load_lds(
      (const __attribute__((address_space(1))) void*)g,
      (__attribute__((address_space(3))) void*)l, 16, 0, 0);
}

__device__ __forceinline__ u16 f2h(float f) {
  _Float16 h = (_Float16)f;
  return __builtin_bit_cast(u16, h);
}

// ---- prep_w: W[oc][ic][3][3] fp32 -> Wt fp16 (unchanged from R8).
// Layout = [t 18][octile 2][k8 8][ocl 128][8ic].
__global__ void prep_w(const float* __restrict__ W, u16* __restrict__ Wt,
                       u16* __restrict__ zp) {
  int e = blockIdx.x * 256 + threadIdx.x;     // 1152 * 256 = 294912
  if (blockIdx.x == 0 && threadIdx.x < 128) zp[threadIdx.x] = 0;
  int j   = e & 7;
  int ocl = (e >> 3) & 127;
  int k8  = (e >> 10) & 7;
  int o   = (e >> 13) & 1;
  int t   = e >> 14;                          // 0..17
  int oc = o * 128 + ocl;
  int ic = (t & 1) * 64 + k8 * 8 + j;
  Wt[e] = f2h(W[(oc * CIN + ic) * 9 + (t >> 1)]);
}

// ---- prep_x: x NCHW fp32 -> xt [n][g=ic/8][pix][8ic] fp16 (unchanged).
__global__ void prep_x(const float* __restrict__ x, u16* __restrict__ xt) {
  __shared__ unsigned int tile[64 * 65];      // [pix][icpair], +1 pad
  int b = blockIdx.x;                         // 1568 = 32 * 49
  int n = b / 49;
  int hw0 = (b % 49) * 64;
  int tid = threadIdx.x;
  const float* xb = x + (size_t)n * CIN * NPIX + hw0;
  #pragma unroll
  for (int i = 0; i < 16; ++i) {
    int e = tid + i * 256;
    int icp = e >> 6;
    int pix = e & 63;
    float a = xb[(size_t)(2 * icp) * NPIX + pix];
    float c = xb[(size_t)(2 * icp + 1) * NPIX + pix];
    tile[pix * 65 + icp] = (unsigned)f2h(a) | ((unsigned)f2h(c) << 16);
  }
  __syncthreads();
  #pragma unroll
  for (int i = 0; i < 4; ++i) {
    int e = tid + i * 256;
    int g = e >> 6;
    int pix = e & 63;
    uint4 v;
    v.x = tile[pix * 65 + g * 4 + 0];
    v.y = tile[pix * 65 + g * 4 + 1];
    v.z = tile[pix * 65 + g * 4 + 2];
    v.w = tile[pix * 65 + g * 4 + 3];
    *(uint4*)(xt + ((size_t)(n * 16 + g) * NPIX + hw0 + pix) * 8) = v;
  }
}

__global__ __launch_bounds__(512, 4) void conv_mfma(
    const u16* __restrict__ Wt, const u16* __restrict__ xt,
    const float* __restrict__ bias, float* __restrict__ out,
    const u16* __restrict__ zp) {
  __shared__ __align__(16) u16 lds[16384];    // A double-buffer: 2 x 16KB

  int tid  = threadIdx.x;                     // 0..511
  int lane = tid & 63;
  int wv   = tid >> 6;                        // 0..7
  int bid  = blockIdx.x;                      // 0..783
  int wgid = (bid & 7) * 98 + (bid >> 3);     // XCD swizzle (784 = 8*98)
  int octile = wgid & 1;                      // same-XCD pair shares ptile
  int ptile  = wgid >> 1;                     // 0..391

  int wm = wv >> 2, wn = wv & 3;              // 2M x 4N waves, per-wave 64x64
  int l15 = lane & 15, lg = lane >> 4;

  const char* xtb  = (const char*)xt;
  const char* zpc  = (const char*)zp;
  const char* wsrc = (const char*)Wt + (size_t)octile * 16384 + tid * 16;

  // Per-lane B geometry: byte offset of granule (n*16+lg, pix[nf]) in xt,
  // plus a 36-bit per-lane tap-validity mask (4 nf x 9 taps).
  unsigned boff[4];
  unsigned long long vmask = 0ull;
  #pragma unroll
  for (int nf = 0; nf < 4; ++nf) {
    int p = ptile * 256 + wn * 64 + nf * 16 + l15;
    int n = p / NPIX, r = p % NPIX, y = r / HW, x = r % HW;
    boff[nf] = (unsigned)(((n * 16 + lg) * NPIX + r) * 16);
    #pragma unroll
    for (int tap = 0; tap < 9; ++tap) {
      int dh = tap / 3 - 1, dw = tap % 3 - 1;
      unsigned long long ok =
          ((unsigned)(y + dh) < HW && (unsigned)(x + dw) < HW) ? 1ull : 0ull;
      vmask |= ok << (nf * 9 + tap);
    }
  }

  auto stageA = [&](int t) {                  // 1024 granules, 2/thread
    const char* src = wsrc + (size_t)t * 32768;
    u16* dst = &lds[(t & 1) * 8192 + tid * 8];
    gload16(src, dst);
    gload16(src + 8192, dst + 4096);
  };

  f32x4 acc[4][4] = {};

  stageA(0);
  WAITVM0; BARRIER;

  for (int t = 0; t < NKT; ++t) {
    int tap = t >> 1, ich = t & 1;
    int dh = tap / 3 - 1, dw = tap % 3 - 1;
    int sh16 = ((dh * HW + dw) + ich * 8 * NPIX) * 16;   // wave-uniform
    const u16* abase = &lds[(t & 1) * 8192];
    if (t + 1 < NKT) stageA(t + 1);
    #pragma unroll
    for (int kk = 0; kk < 2; ++kk) {
      f16x8 bf[4], af[4];
      #pragma unroll
      for (int nf = 0; nf < 4; ++nf) {        // B direct from L2/L3
        bool ok = (vmask >> (nf * 9 + tap)) & 1ull;
        const char* sp = ok ? xtb + ((int)boff[nf] + sh16 + kk * 4 * NPIX * 16)
                            : zpc;
        bf[nf] = *(const f16x8*)sp;
      }
      #pragma unroll
      for (int q = 0; q < 4; ++q)             // A from LDS (4x reuse)
        af[q] = *(const f16x8*)
            &abase[((kk * 4 + lg) * 128 + wm * 64 + q * 16 + l15) * 8];
      __builtin_amdgcn_s_setprio(1);
      #pragma unroll
      for (int mq = 0; mq < 4; ++mq)
        #pragma unroll
        for (int nf = 0; nf < 4; ++nf)
          acc[mq][nf] = __builtin_amdgcn_mfma_f32_16x16x32_f16(
              af[mq], bf[nf], acc[mq][nf], 0, 0, 0);
      __builtin_amdgcn_s_setprio(0);
    }
    WAITVM0;                                  // stageA(t+1) landed
    BARRIER;                                  // one barrier per K-tile
  }

  // Epilogue. C/D: row(oc) = lg*4 + reg, col(pix) = l15.
  float* ob[4];
  #pragma unroll
  for (int nf = 0; nf < 4; ++nf) {
    int pp = ptile * 256 + wn * 64 + nf * 16 + l15;
    int nn = pp / NPIX, hw = pp % NPIX;
    ob[nf] = out + (size_t)nn * COUT * NPIX + hw;
  }
  #pragma unroll
  for (int mq = 0; mq < 4; ++mq) {
    int oc = octile * 128 + wm * 64 + mq * 16 + lg * 4;
    f32x4 bv = *(const f32x4*)&bias[oc];
    #pragma unroll
    for (int rr = 0; rr < 4; ++rr) {
      size_t row = (size_t)(oc + rr) * NPIX;
      #pragma unroll
      for (int nf = 0; nf < 4; ++nf)
        ob[nf][row] = acc[mq][nf][rr] + bv[rr];
    }
  }
}

// ---- fallback (only if ws too small): naive fp32 direct conv
__global__ void conv_naive(const float* __restrict__ x, const float* __restrict__ W,
                           const float* __restrict__ b, float* __restrict__ out) {
  int idx = blockIdx.x * 256 + threadIdx.x;
  int hw = idx % NPIX;
  int tmp = idx / NPIX;
  int oc = tmp % COUT;
  int n = tmp / COUT;
  int h = hw / HW, w = hw % HW;
  float acc = b[oc];
  for (int ic = 0; ic < CIN; ++ic) {
    const float* xr = x + (size_t)(n * CIN + ic) * NPIX;
    const float* wr = W + (size_t)(oc * CIN + ic) * 9;
    #pragma unroll
    for (int kh = 0; kh < 3; ++kh) {
      int ih = h + kh - 1;
      if ((unsigned)ih >= HW) continue;
      #pragma unroll
      for (int kw = 0; kw < 3; ++kw) {
        int iw = w + kw - 1;
        if ((unsigned)iw >= HW) continue;
        acc += xr[ih * HW + iw] * wr[kh * 3 + kw];
      }
    }
  }
  out[idx] = acc;
}

extern "C" void kernel_launch(void* const* d_in, const int* in_sizes, int n_in,
                              void* d_out, int out_size, void* d_ws, size_t ws_size,
                              hipStream_t stream) {
  const float* x = (const float*)d_in[0];
  const float* W = (const float*)d_in[1];
  const float* b = (const float*)d_in[2];
  float* out = (float*)d_out;

  const size_t ZP_OFF = 0;                    // 256 B zero page
  const size_t WT_OFF = 256;                  // 294912 * 2 = 589824 B
  const size_t XT_OFF = 256 + 589824;
  const size_t NEED = XT_OFF + (size_t)TOTPIX * CIN * 2;  // ~26.3 MB

  if (ws_size < NEED) {
    conv_naive<<<TOTPIX * COUT / 256, 256, 0, stream>>>(x, W, b, out);
    return;
  }
  char* ws = (char*)d_ws;
  u16* zp = (u16*)(ws + ZP_OFF);
  u16* Wt = (u16*)(ws + WT_OFF);
  u16* xt = (u16*)(ws + XT_OFF);

  prep_w<<<1152, 256, 0, stream>>>(W, Wt, zp);
  prep_x<<<1568, 256, 0, stream>>>(x, xt);
  conv_mfma<<<784, 512, 0, stream>>>(Wt, xt, b, out, zp);
}

// Round 11
// 101.342 us; speedup vs baseline: 1.0323x; 1.0323x over previous
//
#include <hip/hip_runtime.h>

// MyConv2D: N=32, Cin=128, H=W=56, Cout=256, K=3, stride=1, pad=1, fp32.
// R11: back to R8 base (best: 73.7us; R10's B-direct regressed to 86.9) plus:
// (1) T3-minimum pipeline: BK=32 double-buffered LDS (24KB/buf, 48KB/block,
//     2 blocks/CU), stage(s+1) BEFORE compute(s), single vmcnt(0)+barrier
//     per tile — stage latency hidden under compute.
// (2) 32x32x16 MFMA: half the MFMA instructions, ~17% fewer matrix-pipe
//     cycles (8.07 cyc/32kFLOP vs 2x4.85), same acc budget (4x f32x16 = 64).
// Fragment granule = 8 consecutive ic = one 16B granule (same prep layouts).

typedef unsigned short u16;
typedef _Float16 f16x8 __attribute__((ext_vector_type(8)));
typedef float f32x4 __attribute__((ext_vector_type(4)));
typedef float f32x16 __attribute__((ext_vector_type(16)));

#define CIN    128
#define COUT   256
#define HW     56
#define NPIX   3136        // 56*56
#define TOTPIX 100352      // 32*3136
#define NKT    36          // K-tiles of 32 ic: 9 taps * 4 ic-quarters

#define WAITVM0 asm volatile("s_waitcnt vmcnt(0)" ::: "memory")
#define BARRIER asm volatile("s_barrier" ::: "memory")

__device__ __forceinline__ void gload16(const void* g, void* l) {
  __builtin_amdgcn_global_load_lds(
      (const __attribute__((address_space(1))) void*)g,
      (__attribute__((address_space(3))) void*)l, 16, 0, 0);
}

__device__ __forceinline__ u16 f2h(float f) {
  _Float16 h = (_Float16)f;
  return __builtin_bit_cast(u16, h);
}

// ---- prep_w: W[oc][ic][3][3] fp32 -> Wt fp16 (unchanged layout).
// Wt granule layout: [t18][octile 2][k8 8][ocl 128] (16B granules).
__global__ void prep_w(const float* __restrict__ W, u16* __restrict__ Wt,
                       u16* __restrict__ zp) {
  int e = blockIdx.x * 256 + threadIdx.x;     // 1152 * 256 = 294912
  if (blockIdx.x == 0 && threadIdx.x < 128) zp[threadIdx.x] = 0;
  int j   = e & 7;
  int ocl = (e >> 3) & 127;
  int k8  = (e >> 10) & 7;
  int o   = (e >> 13) & 1;
  int t   = e >> 14;                          // 0..17
  int oc = o * 128 + ocl;
  int ic = (t & 1) * 64 + k8 * 8 + j;
  Wt[e] = f2h(W[(oc * CIN + ic) * 9 + (t >> 1)]);
}

// ---- prep_x: x NCHW fp32 -> xt [n][g=ic/8][pix][8ic] fp16 (unchanged).
__global__ void prep_x(const float* __restrict__ x, u16* __restrict__ xt) {
  __shared__ unsigned int tile[64 * 65];      // [pix][icpair], +1 pad
  int b = blockIdx.x;                         // 1568 = 32 * 49
  int n = b / 49;
  int hw0 = (b % 49) * 64;
  int tid = threadIdx.x;
  const float* xb = x + (size_t)n * CIN * NPIX + hw0;
  #pragma unroll
  for (int i = 0; i < 16; ++i) {
    int e = tid + i * 256;
    int icp = e >> 6;
    int pix = e & 63;
    float a = xb[(size_t)(2 * icp) * NPIX + pix];
    float c = xb[(size_t)(2 * icp + 1) * NPIX + pix];
    tile[pix * 65 + icp] = (unsigned)f2h(a) | ((unsigned)f2h(c) << 16);
  }
  __syncthreads();
  #pragma unroll
  for (int i = 0; i < 4; ++i) {
    int e = tid + i * 256;
    int g = e >> 6;
    int pix = e & 63;
    uint4 v;
    v.x = tile[pix * 65 + g * 4 + 0];
    v.y = tile[pix * 65 + g * 4 + 1];
    v.z = tile[pix * 65 + g * 4 + 2];
    v.w = tile[pix * 65 + g * 4 + 3];
    *(uint4*)(xt + ((size_t)(n * 16 + g) * NPIX + hw0 + pix) * 8) = v;
  }
}

__global__ __launch_bounds__(512, 4) void conv_mfma(
    const u16* __restrict__ Wt, const u16* __restrict__ xt,
    const float* __restrict__ bias, float* __restrict__ out,
    const u16* __restrict__ zp) {
  // Per buffer (12288 u16 = 24KB): A [k8' 4][ocl 128][8] at 0,
  //                                B [k8' 4][pixl 256][8] at 4096.
  __shared__ __align__(16) u16 lds[24576];    // 2 buffers, 48KB

  int tid  = threadIdx.x;                     // 0..511
  int lane = tid & 63;
  int wv   = tid >> 6;                        // 0..7
  int bid  = blockIdx.x;                      // 0..783
  int wgid = (bid & 7) * 98 + (bid >> 3);     // XCD swizzle (784 = 8*98)
  int octile = wgid & 1;                      // same-XCD pair shares ptile
  int ptile  = wgid >> 1;                     // 0..391

  int wm = wv >> 2, wn = wv & 3;              // 2M x 4N waves, per-wave 64x64
  int l31 = lane & 31, lh = lane >> 5;

  // Staging geometry.
  // A: 512 granules/tile, 1/thread: k8' = tid>>7, ocl = tid&127.
  // B: 1024 granules/tile, 2/thread: pix = tid&255, k8' = (tid>>8) + 2i.
  int spix = tid & 255;
  int p = ptile * 256 + spix;
  int sn = p / NPIX, sr = p % NPIX, sy = sr / HW, sx = sr % HW;
  const char* xtb  = (const char*)xt;
  const char* zpc  = (const char*)zp;
  const char* wbase = (const char*)Wt + (size_t)octile * 16384 +
                      ((tid >> 7) * 128 + (tid & 127)) * 16;

  auto stage = [&](int s, int buf) {
    // A granule: t = s>>1, k8 = (s&1)*4 + k8'.
    const char* asrc = wbase + (size_t)(s >> 1) * 32768 + (s & 1) * 8192;
    gload16(asrc, &lds[buf * 12288 + tid * 8]);
    // B granules: tap = s>>2, icq = s&3, g = icq*4 + k8'_i.
    int tap = s >> 2, icq = s & 3;
    int t3 = tap / 3;
    int dh = t3 - 1, dw = (tap - t3 * 3) - 1;
    bool ok = (unsigned)(sy + dh) < HW && (unsigned)(sx + dw) < HW;
    const char* bsrc = ok
        ? xtb + ((size_t)(sn * 16 + icq * 4 + (tid >> 8)) * NPIX +
                 (sr + dh * HW + dw)) * 16
        : zpc;
    size_t step = ok ? (size_t)2 * NPIX * 16 : 0;
    u16* bdst = &lds[buf * 12288 + 4096 + ((tid >> 8) * 256 + spix) * 8];
    gload16(bsrc, bdst);
    gload16(bsrc + step, bdst + 2 * 256 * 8);
  };

  f32x16 acc[2][2] = {};

  stage(0, 0);
  WAITVM0; BARRIER;

  #pragma unroll 4
  for (int s = 0; s < NKT; ++s) {
    int buf = s & 1;
    if (s + 1 < NKT) stage(s + 1, buf ^ 1);
    const u16* base = &lds[buf * 12288];
    #pragma unroll
    for (int ks = 0; ks < 2; ++ks) {
      int k8 = 2 * ks + lh;
      f16x8 af[2], bf[2];
      #pragma unroll
      for (int mq = 0; mq < 2; ++mq)
        af[mq] = *(const f16x8*)&base[(k8 * 128 + wm * 64 + mq * 32 + l31) * 8];
      #pragma unroll
      for (int nf = 0; nf < 2; ++nf)
        bf[nf] = *(const f16x8*)
            &base[4096 + (k8 * 256 + wn * 64 + nf * 32 + l31) * 8];
      __builtin_amdgcn_s_setprio(1);
      #pragma unroll
      for (int mq = 0; mq < 2; ++mq)
        #pragma unroll
        for (int nf = 0; nf < 2; ++nf)
          acc[mq][nf] = __builtin_amdgcn_mfma_f32_32x32x16_f16(
              af[mq], bf[nf], acc[mq][nf], 0, 0, 0);
      __builtin_amdgcn_s_setprio(0);
    }
    WAITVM0;                                  // stage(s+1) landed (covered)
    BARRIER;                                  // one barrier per K-tile
  }

  // Epilogue. 32x32 C/D: col(pix) = lane&31, row(oc) = (r&3)+8*(r>>2)+4*lh.
  float* ob[2];
  #pragma unroll
  for (int nf = 0; nf < 2; ++nf) {
    int pp = ptile * 256 + wn * 64 + nf * 32 + l31;
    int nn = pp / NPIX, hw = pp % NPIX;
    ob[nf] = out + (size_t)nn * COUT * NPIX + hw;
  }
  #pragma unroll
  for (int mq = 0; mq < 2; ++mq) {
    #pragma unroll
    for (int rq = 0; rq < 4; ++rq) {
      int ocg = octile * 128 + wm * 64 + mq * 32 + rq * 8 + lh * 4;
      f32x4 bv = *(const f32x4*)&bias[ocg];
      #pragma unroll
      for (int j = 0; j < 4; ++j) {
        size_t row = (size_t)(ocg + j) * NPIX;
        #pragma unroll
        for (int nf = 0; nf < 2; ++nf)
          ob[nf][row] = acc[mq][nf][rq * 4 + j] + bv[j];
      }
    }
  }
}

// ---- fallback (only if ws too small): naive fp32 direct conv
__global__ void conv_naive(const float* __restrict__ x, const float* __restrict__ W,
                           const float* __restrict__ b, float* __restrict__ out) {
  int idx = blockIdx.x * 256 + threadIdx.x;
  int hw = idx % NPIX;
  int tmp = idx / NPIX;
  int oc = tmp % COUT;
  int n = tmp / COUT;
  int h = hw / HW, w = hw % HW;
  float acc = b[oc];
  for (int ic = 0; ic < CIN; ++ic) {
    const float* xr = x + (size_t)(n * CIN + ic) * NPIX;
    const float* wr = W + (size_t)(oc * CIN + ic) * 9;
    #pragma unroll
    for (int kh = 0; kh < 3; ++kh) {
      int ih = h + kh - 1;
      if ((unsigned)ih >= HW) continue;
      #pragma unroll
      for (int kw = 0; kw < 3; ++kw) {
        int iw = w + kw - 1;
        if ((unsigned)iw >= HW) continue;
        acc += xr[ih * HW + iw] * wr[kh * 3 + kw];
      }
    }
  }
  out[idx] = acc;
}

extern "C" void kernel_launch(void* const* d_in, const int* in_sizes, int n_in,
                              void* d_out, int out_size, void* d_ws, size_t ws_size,
                              hipStream_t stream) {
  const float* x = (const float*)d_in[0];
  const float* W = (const float*)d_in[1];
  const float* b = (const float*)d_in[2];
  float* out = (float*)d_out;

  const size_t ZP_OFF = 0;                    // 256 B zero page
  const size_t WT_OFF = 256;                  // 294912 * 2 = 589824 B
  const size_t XT_OFF = 256 + 589824;
  const size_t NEED = XT_OFF + (size_t)TOTPIX * CIN * 2;  // ~26.3 MB

  if (ws_size < NEED) {
    conv_naive<<<TOTPIX * COUT / 256, 256, 0, stream>>>(x, W, b, out);
    return;
  }
  char* ws = (char*)d_ws;
  u16* zp = (u16*)(ws + ZP_OFF);
  u16* Wt = (u16*)(ws + WT_OFF);
  u16* xt = (u16*)(ws + XT_OFF);

  prep_w<<<1152, 256, 0, stream>>>(W, Wt, zp);
  prep_x<<<1568, 256, 0, stream>>>(x, xt);
  conv_mfma<<<784, 512, 0, stream>>>(Wt, xt, b, out, zp);
}

// Round 16
// 90.632 us; speedup vs baseline: 1.1543x; 1.1182x over previous
//
#include <hip/hip_runtime.h>

// MyConv2D: N=32, Cin=128, H=W=56, Cout=256, K=3, stride=1, pad=1, fp32.
// R16 == R12..R15 resubmit (all failed pre-push on container infra).
// R8's proven loop (BK=64, single-buffer, 2 barriers/tile, 16x16x32)
// at HALF block size: 128(oc)x128(pix) tile, 256 thr / 4 waves, per-wave
// 64x64, 32KB LDS -> 4 blocks/CU (vs R8's 2) and 1568 finer-grained blocks
// (tail quantization 31%->~10%, 4-wave barriers, 4-way cross-block overlap).
// prep_x LDS-free (strided coalesced read -> pack -> 16B store).

typedef unsigned short u16;
typedef _Float16 f16x8 __attribute__((ext_vector_type(8)));
typedef float f32x4 __attribute__((ext_vector_type(4)));

#define CIN    128
#define COUT   256
#define HW     56
#define NPIX   3136        // 56*56
#define TOTPIX 100352      // 32*3136
#define NKT    18          // K-tiles of 64 ic: 9 taps * 2 ic-halves

#define WAITVM0 asm volatile("s_waitcnt vmcnt(0)" ::: "memory")
#define BARRIER asm volatile("s_barrier" ::: "memory")

__device__ __forceinline__ void gload16(const void* g, void* l) {
  __builtin_amdgcn_global_load_lds(
      (const __attribute__((address_space(1))) void*)g,
      (__attribute__((address_space(3))) void*)l, 16, 0, 0);
}

__device__ __forceinline__ u16 f2h(float f) {
  _Float16 h = (_Float16)f;
  return __builtin_bit_cast(u16, h);
}

// ---- prep_w: W[oc][ic][3][3] fp32 -> Wt fp16 (unchanged layout).
// Wt granules: [t 18][octile 2][k8 8][ocl 128], 16B each.
__global__ void prep_w(const float* __restrict__ W, u16* __restrict__ Wt,
                       u16* __restrict__ zp) {
  int e = blockIdx.x * 256 + threadIdx.x;     // 1152 * 256 = 294912
  if (blockIdx.x == 0 && threadIdx.x < 128) zp[threadIdx.x] = 0;
  int j   = e & 7;
  int ocl = (e >> 3) & 127;
  int k8  = (e >> 10) & 7;
  int o   = (e >> 13) & 1;
  int t   = e >> 14;                          // 0..17
  int oc = o * 128 + ocl;
  int ic = (t & 1) * 64 + k8 * 8 + j;
  Wt[e] = f2h(W[(oc * CIN + ic) * 9 + (t >> 1)]);
}

// ---- prep_x: x NCHW fp32 -> xt [n][g=ic/8][pix][8ic] fp16, LDS-free.
// 2048 blocks: (n 32, g 16, chunk 4 of 784 pix). Reads 8 strided rows
// (each wave-coalesced), packs fp16 pairs, one 16B store per pixel.
__global__ void prep_x(const float* __restrict__ x, u16* __restrict__ xt) {
  int b = blockIdx.x;
  int n = b >> 6, g = (b >> 2) & 15, c = b & 3;
  const float* xs = x + ((size_t)(n * 16 + g) * 8) * NPIX;
  u16* xd = xt + ((size_t)(n * 16 + g) * NPIX) * 8;
  #pragma unroll
  for (int i = 0; i < 4; ++i) {
    int off = i * 256 + (int)threadIdx.x;     // 784 = 3*256 + 16
    if (off < 784) {
      int pix = c * 784 + off;
      unsigned q0, q1, q2, q3;
      q0 = (unsigned)f2h(xs[(size_t)0 * NPIX + pix]) |
           ((unsigned)f2h(xs[(size_t)1 * NPIX + pix]) << 16);
      q1 = (unsigned)f2h(xs[(size_t)2 * NPIX + pix]) |
           ((unsigned)f2h(xs[(size_t)3 * NPIX + pix]) << 16);
      q2 = (unsigned)f2h(xs[(size_t)4 * NPIX + pix]) |
           ((unsigned)f2h(xs[(size_t)5 * NPIX + pix]) << 16);
      q3 = (unsigned)f2h(xs[(size_t)6 * NPIX + pix]) |
           ((unsigned)f2h(xs[(size_t)7 * NPIX + pix]) << 16);
      uint4 v; v.x = q0; v.y = q1; v.z = q2; v.w = q3;
      *(uint4*)(xd + (size_t)pix * 8) = v;
    }
  }
}

__global__ __launch_bounds__(256, 4) void conv_mfma(
    const u16* __restrict__ Wt, const u16* __restrict__ xt,
    const float* __restrict__ bias, float* __restrict__ out,
    const u16* __restrict__ zp) {
  // 32KB single buffer: A [k8 8][ocl 128][8] at 0 | B [k8 8][pixl 128][8] at 8192.
  __shared__ __align__(16) u16 lds[16384];

  int tid  = threadIdx.x;                     // 0..255
  int lane = tid & 63;
  int wv   = tid >> 6;                        // 0..3
  int bid  = blockIdx.x;                      // 0..1567
  int wgid = (bid & 7) * 196 + (bid >> 3);    // XCD swizzle (1568 = 8*196)
  int octile = wgid & 1;                      // same-XCD pair shares B panel
  int ptile  = wgid >> 1;                     // 0..783

  int wm = wv >> 1, wn = wv & 1;              // 2M x 2N waves, per-wave 64x64
  int l15 = lane & 15, lg = lane >> 4;

  // B staging: thread owns pixel spix = tid&127, g = (tid>>7) + 2i (i=0..3).
  int spix = tid & 127;
  int p = ptile * 128 + spix;
  int sn = p / NPIX, sr = p % NPIX, sy = sr / HW, sx = sr % HW;
  const char* xtb = (const char*)xt;
  const char* zpc = (const char*)zp;
  // A staging: granules linear, 4/thread: (k8*128+ocl) = tid + i*256.
  const char* wbase = (const char*)Wt + (size_t)octile * 16384 + tid * 16;

  auto stage = [&](int t) {
    const char* asrc = wbase + (size_t)t * 32768;
    #pragma unroll
    for (int i = 0; i < 4; ++i)
      gload16(asrc + i * 4096, &lds[tid * 8 + i * 2048]);
    int tap = t >> 1, ich = t & 1;
    int t3 = tap / 3;
    int dh = t3 - 1, dw = (tap - t3 * 3) - 1;
    bool ok = (unsigned)(sy + dh) < HW && (unsigned)(sx + dw) < HW;
    const char* bsrc = ok
        ? xtb + ((size_t)(sn * 16 + ich * 8 + (tid >> 7)) * NPIX +
                 (sr + dh * HW + dw)) * 16
        : zpc;
    size_t step = ok ? (size_t)2 * NPIX * 16 : 0;
    u16* bdst = &lds[8192 + ((tid >> 7) * 128 + spix) * 8];
    #pragma unroll
    for (int i = 0; i < 4; ++i)
      gload16(bsrc + i * step, bdst + i * 2048);  // g+2 -> +2*128 granules
  };

  f32x4 acc[4][4] = {};

  stage(0);
  WAITVM0; BARRIER;

  for (int t = 0; t < NKT; ++t) {
    #pragma unroll
    for (int kk = 0; kk < 2; ++kk) {
      f16x8 af[4], bf[4];
      #pragma unroll
      for (int q = 0; q < 4; ++q)
        af[q] = *(const f16x8*)
            &lds[((kk * 4 + lg) * 128 + wm * 64 + q * 16 + l15) * 8];
      #pragma unroll
      for (int q = 0; q < 4; ++q)
        bf[q] = *(const f16x8*)
            &lds[8192 + ((kk * 4 + lg) * 128 + wn * 64 + q * 16 + l15) * 8];
      __builtin_amdgcn_s_setprio(1);
      #pragma unroll
      for (int mq = 0; mq < 4; ++mq)
        #pragma unroll
        for (int nf = 0; nf < 4; ++nf)
          acc[mq][nf] = __builtin_amdgcn_mfma_f32_16x16x32_f16(
              af[mq], bf[nf], acc[mq][nf], 0, 0, 0);
      __builtin_amdgcn_s_setprio(0);
    }
    if (t + 1 < NKT) {
      BARRIER;                                // all waves done reading tile t
      stage(t + 1);
      WAITVM0; BARRIER;                       // tile t+1 in LDS
    }
  }

  // Epilogue. C/D: row(oc) = lg*4 + reg, col(pix) = l15.
  float* ob[4];
  #pragma unroll
  for (int nf = 0; nf < 4; ++nf) {
    int pp = ptile * 128 + wn * 64 + nf * 16 + l15;
    int nn = pp / NPIX, hw = pp % NPIX;
    ob[nf] = out + (size_t)nn * COUT * NPIX + hw;
  }
  #pragma unroll
  for (int mq = 0; mq < 4; ++mq) {
    int oc = octile * 128 + wm * 64 + mq * 16 + lg * 4;
    f32x4 bv = *(const f32x4*)&bias[oc];
    #pragma unroll
    for (int rr = 0; rr < 4; ++rr) {
      size_t row = (size_t)(oc + rr) * NPIX;
      #pragma unroll
      for (int nf = 0; nf < 4; ++nf)
        ob[nf][row] = acc[mq][nf][rr] + bv[rr];
    }
  }
}

// ---- fallback (only if ws too small): naive fp32 direct conv
__global__ void conv_naive(const float* __restrict__ x, const float* __restrict__ W,
                           const float* __restrict__ b, float* __restrict__ out) {
  int idx = blockIdx.x * 256 + threadIdx.x;
  int hw = idx % NPIX;
  int tmp = idx / NPIX;
  int oc = tmp % COUT;
  int n = tmp / COUT;
  int h = hw / HW, w = hw % HW;
  float acc = b[oc];
  for (int ic = 0; ic < CIN; ++ic) {
    const float* xr = x + (size_t)(n * CIN + ic) * NPIX;
    const float* wr = W + (size_t)(oc * CIN + ic) * 9;
    #pragma unroll
    for (int kh = 0; kh < 3; ++kh) {
      int ih = h + kh - 1;
      if ((unsigned)ih >= HW) continue;
      #pragma unroll
      for (int kw = 0; kw < 3; ++kw) {
        int iw = w + kw - 1;
        if ((unsigned)iw >= HW) continue;
        acc += xr[ih * HW + iw] * wr[kh * 3 + kw];
      }
    }
  }
  out[idx] = acc;
}

extern "C" void kernel_launch(void* const* d_in, const int* in_sizes, int n_in,
                              void* d_out, int out_size, void* d_ws, size_t ws_size,
                              hipStream_t stream) {
  const float* x = (const float*)d_in[0];
  const float* W = (const float*)d_in[1];
  const float* b = (const float*)d_in[2];
  float* out = (float*)d_out;

  const size_t ZP_OFF = 0;                    // 256 B zero page
  const size_t WT_OFF = 256;                  // 294912 * 2 = 589824 B
  const size_t XT_OFF = 256 + 589824;
  const size_t NEED = XT_OFF + (size_t)TOTPIX * CIN * 2;  // ~26.3 MB

  if (ws_size < NEED) {
    conv_naive<<<TOTPIX * COUT / 256, 256, 0, stream>>>(x, W, b, out);
    return;
  }
  char* ws = (char*)d_ws;
  u16* zp = (u16*)(ws + ZP_OFF);
  u16* Wt = (u16*)(ws + WT_OFF);
  u16* xt = (u16*)(ws + XT_OFF);

  prep_w<<<1152, 256, 0, stream>>>(W, Wt, zp);
  prep_x<<<2048, 256, 0, stream>>>(x, xt);
  conv_mfma<<<1568, 256, 0, stream>>>(Wt, xt, b, out, zp);
}